// Round 20
// baseline (117.829 us; speedup 1.0000x reference)
//
#include <hip/hip_runtime.h>

#define CI 32
#define CO 32
#define PD 64
#define QDIM 1024
#define M_TOTAL (32*4096)
#define TILE_M 128                 // per WG: waves = (rg 0..1) x (ih 0..1)
#define NBLK (M_TOTAL/TILE_M)      // 1024 WGs; supply 16 waves/CU
#define WG_THREADS 256
#define XLS 33                     // Xl[m][i]: reads (l31+i)%32 conflict-free
#define OLS 33                     // U.o[lane][r]: 2-way free

typedef float  f32x2  __attribute__((ext_vector_type(2)));
typedef float  f32x4  __attribute__((ext_vector_type(4)));
typedef float  f32x16 __attribute__((ext_vector_type(16)));
typedef __bf16 bf16x4 __attribute__((ext_vector_type(4)));
typedef __bf16 bf16x8 __attribute__((ext_vector_type(8)));

// ---- one-time: Wk [64][1024] f32 -> wsF, MFMA-A-fragment-linear layout ----
__global__ __launch_bounds__(256)
void wk_pack_kernel(const float* __restrict__ Wk, __bf16* __restrict__ wsF)
{
    __shared__ float tile[64][33];
    const int q0 = blockIdx.x * 32;
    const int t  = threadIdx.x;
#pragma unroll
    for (int s = 0; s < 2; ++s) {
        const int idx = t + s * 256;
        const int k = idx >> 3, ch = idx & 7;
        f32x4 v = *(const f32x4*)(Wk + (size_t)k * QDIM + q0 + ch * 4);
        tile[k][ch*4+0] = v[0]; tile[k][ch*4+1] = v[1];
        tile[k][ch*4+2] = v[2]; tile[k][ch*4+3] = v[3];
    }
    __syncthreads();
    const int qq = t >> 3;
    const int g  = t & 7;
    bf16x8 o;
#pragma unroll
    for (int j = 0; j < 8; ++j) o[j] = (__bf16)tile[g*8 + j][qq];
    *(bf16x8*)(wsF + (size_t)blockIdx.x * 2048 + g * 256 + qq * 8) = o;
}

// MEASUREMENT ROUND: main <1,false> = R19 best (packed epilogue). diag
// <4,true> = identical structure, i-loop x4 (≈120us -> tops the dispatch
// table past the 39us harness fills), sink-write so nothing is DCE'd.
// Goal: first-ever counters (VGPR/Occupancy/MfmaUtil/VALUBusy) for the
// actual best binary. DO NOT: min-waves 4 (R16 spills), X per-lane global
// (R18 scatter), scalar Wk gathers in-loop (R6).
template <int REPS, bool DIAG>
__global__ __launch_bounds__(WG_THREADS, 2)
void cond_body(const float* __restrict__ Xg, const float* __restrict__ Pg,
               const __bf16* __restrict__ wsF, float* __restrict__ outg)
{
    __shared__ union {
        __bf16 p[TILE_M * PD];       // 16384 B: P-tile (dead after bfrag)
        float  o[2 * 64 * OLS];      // 16896 B: partial-sum exchange
    } U;
    __shared__ float Xl[TILE_M * XLS];   // 16896 B: X row-major [m][i]

    const int t   = threadIdx.x;
    const int l   = t & 63;
    const int w   = t >> 6;
    const int rg  = w & 1;          // row-group: rows rg*64 .. rg*64+63
    const int ih  = w >> 1;         // i-half: i in ih*16 .. ih*16+15
    const int l31 = l & 31;
    const int hi  = l >> 5;
    const int tile0 = blockIdx.x * TILE_M;
    const int m0  = rg * 64 + l31;  // lane's first row (second = m0+32)

    // ---- stage: P[128][64] -> bf16 swizzled; X[128][32] -> Xl[m][i] ----
    {
        const float* Pb = Pg + (size_t)tile0 * PD;
#pragma unroll
        for (int s = 0; s < 8; ++s) {
            const int id = t + 256 * s;
            const int r = id >> 4, ch = id & 15;
            f32x4 v = *(const f32x4*)(Pb + (size_t)r * PD + ch * 4);
            bf16x4 bv;
#pragma unroll
            for (int j = 0; j < 4; ++j) bv[j] = (__bf16)v[j];
            char* dst = (char*)U.p + r * 128
                      + ((((ch >> 1) ^ (r & 7)) << 4) | ((ch & 1) * 8));
            *(bf16x4*)dst = bv;
        }
        const float* Xb = Xg + (size_t)tile0 * CI;
#pragma unroll
        for (int s = 0; s < 4; ++s) {
            const int id = t + 256 * s;
            const int r = id >> 3, ch = id & 7;
            f32x4 v = *(const f32x4*)(Xb + (size_t)r * CI + ch * 4);
#pragma unroll
            for (int j = 0; j < 4; ++j) Xl[r * XLS + ch * 4 + j] = v[j];
        }
    }
    __syncthreads();

    // ---- B fragments (P^T) for rows m0, m0+32 ----
    bf16x8 bfA[4], bfB[4];
#pragma unroll
    for (int kq = 0; kq < 4; ++kq) {
        const int g = ((kq * 2 + hi) ^ (l31 & 7)) << 4;
        bfA[kq] = *(const bf16x8*)((const char*)U.p + m0 * 128 + g);
        bfB[kq] = *(const bf16x8*)((const char*)U.p + (m0 + 32) * 128 + g);
    }

    // ---- i-loop over this wave's half: 16 steps, 2-deep A prefetch ----
    f32x2 oA[8] = {}, oB[8] = {};   // packed accumulators
    const __bf16* abase = wsF + (size_t)(ih * 16) * 2048
                        + (size_t)hi * 256 + (size_t)l31 * 8;
    const float* xb0 = &Xl[m0 * XLS + ih * 16];
    const float* xb1 = &Xl[(m0 + 32) * XLS + ih * 16];

    bf16x8 a0[4], a1[4];
    auto aload = [&](int i, bf16x8* buf) {   // i local 0..15
        const __bf16* ap = abase + (size_t)i * 2048;
        buf[0] = *(const bf16x8*)(ap);
        buf[1] = *(const bf16x8*)(ap +  512);
        buf[2] = *(const bf16x8*)(ap + 1024);
        buf[3] = *(const bf16x8*)(ap + 1536);
    };
    const f32x2 zero2 = {0.0f, 0.0f};
    auto step = [&](const bf16x8* a, int i) {
        const float xl = xb0[i];
        const float xh = xb1[i];
        f32x16 c0 = {}, c1 = {};
#pragma unroll
        for (int kq = 0; kq < 4; ++kq) {
            c0 = __builtin_amdgcn_mfma_f32_32x32x16_bf16(a[kq], bfA[kq], c0, 0, 0, 0);
            c1 = __builtin_amdgcn_mfma_f32_32x32x16_bf16(a[kq], bfB[kq], c1, 0, 0, 0);
        }
        const f32x2 xl2 = {xl, xl}, xh2 = {xh, xh};
#pragma unroll
        for (int r = 0; r < 8; ++r) {
            f32x2 p0 = {c0[2*r], c0[2*r + 1]};
            f32x2 p1 = {c1[2*r], c1[2*r + 1]};
            oA[r] += __builtin_elementwise_max(p0, zero2) * xl2;
            oB[r] += __builtin_elementwise_max(p1, zero2) * xh2;
        }
    };

#pragma unroll 1
    for (int rep = 0; rep < REPS; ++rep) {
        aload(0, a0);
        aload(1, a1);
        for (int ii = 0; ii < 8; ++ii) {
            step(a0, 2 * ii);
            if (ii < 7) aload(2 * ii + 2, a0);
            step(a1, 2 * ii + 1);
            if (ii < 7) aload(2 * ii + 3, a1);
        }
    }

    if (DIAG) {
        // sink write (consumes all accumulators -> no DCE); outg = sink here
        float s = 0;
#pragma unroll
        for (int r = 0; r < 8; ++r)
            s += oA[r][0] + oA[r][1] + oB[r][0] + oB[r][1];
        outg[(size_t)blockIdx.x * WG_THREADS + t] = s;
        return;
    }

    // ---- combine partials: ih=1 publishes, ih=0 adds and stores ----
    __syncthreads();
    if (ih == 1) {
        const int ob = (rg * 64 + l) * OLS;
#pragma unroll
        for (int r = 0; r < 8; ++r) {
            *(f32x2*)&U.o[ob + 2*r]      = oA[r];
            *(f32x2*)&U.o[ob + 16 + 2*r] = oB[r];
        }
    }
    __syncthreads();
    if (ih == 0) {
        const int ob = (rg * 64 + l) * OLS;
#pragma unroll
        for (int r = 0; r < 8; ++r) {
            oA[r] += *(const f32x2*)&U.o[ob + 2*r];
            oB[r] += *(const f32x2*)&U.o[ob + 16 + 2*r];
        }
        float* orow  = outg + (size_t)(tile0 + m0) * CO + 4 * hi;
        float* orow2 = orow + 32 * CO;
#pragma unroll
        for (int rq = 0; rq < 4; ++rq) {
            f32x4 vA, vB;
#pragma unroll
            for (int j = 0; j < 4; ++j) {
                vA[j] = oA[2*rq + (j >> 1)][j & 1];
                vB[j] = oB[2*rq + (j >> 1)][j & 1];
            }
            *(f32x4*)(orow  + 8 * rq) = vA;
            *(f32x4*)(orow2 + 8 * rq) = vB;
        }
    }
}

extern "C" void kernel_launch(void* const* d_in, const int* in_sizes, int n_in,
                              void* d_out, int out_size, void* d_ws, size_t ws_size,
                              hipStream_t stream)
{
    const float* X  = (const float*)d_in[0];
    const float* P  = (const float*)d_in[1];
    const float* Wk = (const float*)d_in[2];
    float* out  = (float*)d_out;
    __bf16* wsF = (__bf16*)d_ws;                          // 128 KB at offset 0
    float* sink = (float*)((char*)d_ws + (16u << 20));    // diag sink at +16 MB

    wk_pack_kernel<<<dim3(QDIM / 32), dim3(256), 0, stream>>>(Wk, wsF);
    cond_body<1, false><<<dim3(NBLK), dim3(WG_THREADS), 0, stream>>>(X, P, wsF, out);
    cond_body<4, true ><<<dim3(NBLK), dim3(WG_THREADS), 0, stream>>>(X, P, wsF, sink);
}

// Round 21
// 41.115 us; speedup vs baseline: 2.8658x; 2.8658x over previous
//
#include <hip/hip_runtime.h>

#define CI 32
#define CO 32
#define PD 64
#define QDIM 1024
#define M_TOTAL (32*4096)
#define TILE_M 256
#define NBLK 256            // 1 persistent WG per CU, 2 tiles each
#define NTILES 2
#define WG_THREADS 256
#define LDS_BYTES 163840    // 128 KiB A-panel + 32 KiB X/P union (AITER-proven size)

typedef float  f32x2  __attribute__((ext_vector_type(2)));
typedef float  f32x4  __attribute__((ext_vector_type(4)));
typedef float  f32x16 __attribute__((ext_vector_type(16)));
typedef __bf16 bf16x4 __attribute__((ext_vector_type(4)));
typedef __bf16 bf16x8 __attribute__((ext_vector_type(8)));

// Dynamic LDS map:
//   [0, 131072)       A-panel bf16, fragment-linear (proven wsF layout):
//                     elem = i*2048 + (k>>3)*256 + (q&31)*8 + (k&7), q = i*32+(q&31)
//   [131072, 163840)  union: X stage f32 [i][m] (32x256)  OR  P stage bf16
//                     swizzled rows (256 x 128 B)   — sequential lifetimes
extern __shared__ char lds_raw[];

// R20 diagnosis: per-XCD L2 sector rate serving A redundantly to every wave
// was the session-long ~21us loop wall. Fix: A shared via LDS once per CU.
// 1 wave/SIMD by design (LDS-bound); VGPR budget free up to 512 (min-waves=1).
// DO NOT: scalar Wk gathers in-loop (R6), min-waves>=4 (R7/R16 spills),
// per-lane X rows from global (R18 scatter).
__global__ __launch_bounds__(WG_THREADS, 1)
void cond_fused(const float* __restrict__ Xg, const float* __restrict__ Pg,
                const float* __restrict__ Wk, float* __restrict__ outg)
{
    __bf16* Al = (__bf16*)lds_raw;
    float*  Ux = (float*)(lds_raw + 131072);
    __bf16* Up = (__bf16*)(lds_raw + 131072);

    const int t   = threadIdx.x;
    const int l   = t & 63;
    const int w   = t >> 6;       // wave 0..3: rows w*64 .. w*64+63 (R=2)
    const int l31 = l & 31;
    const int hi  = l >> 5;       // k-half within K=16 MFMA
    const int m0  = w * 64 + l31; // lane rows: m0, m0+32

    // ---- T14 prefetch regs for P/X staging (96 VGPR in flight) ----
    f32x4 px[16], xx[8];
    auto load_px = [&](int tile0) {
        const float* Pb = Pg + (size_t)tile0 * PD;
        const float* Xb = Xg + (size_t)tile0 * CI;
#pragma unroll
        for (int s = 0; s < 16; ++s) {
            const int id = t + 256 * s;
            px[s] = *(const f32x4*)(Pb + (size_t)(id >> 4) * PD + (id & 15) * 4);
        }
#pragma unroll
        for (int s = 0; s < 8; ++s) {
            const int id = t + 256 * s;
            xx[s] = *(const f32x4*)(Xb + (size_t)(id >> 3) * CI + (id & 7) * 4);
        }
    };

    const int base0 = blockIdx.x * TILE_M;
    load_px(base0);   // in flight during A-pack (T14)

    // ---- A-pack (once): Wk f32 [k][q] -> Al bf16 fragment-linear ----
    // coalesced f32x4 global reads; scattered b16 LDS writes (one-time cost)
    for (int k = 0; k < 64; ++k) {
        f32x4 v = *(const f32x4*)(Wk + (size_t)k * QDIM + t * 4);
#pragma unroll
        for (int j = 0; j < 4; ++j) {
            const int q = t * 4 + j;
            Al[(q >> 5) * 2048 + (k >> 3) * 256 + (q & 31) * 8 + (k & 7)] = (__bf16)v[j];
        }
    }

    for (int tt = 0; tt < NTILES; ++tt) {
        const int tile0 = base0 + tt * (NBLK * TILE_M);
        __syncthreads();    // tt=0: Al+stage writes ordered; tt=1: U reads drained

        // ---- stage X: xx regs -> Ux[i][m] (writes 8-way, one-time) ----
#pragma unroll
        for (int s = 0; s < 8; ++s) {
            const int id = t + 256 * s;
            const int r = id >> 3, ch = id & 7;
#pragma unroll
            for (int j = 0; j < 4; ++j) Ux[(ch * 4 + j) * 256 + r] = xx[s][j];
        }
        __syncthreads();
        // ---- x to regs: 64 x ds_read_b32, bank = m%32 conflict-free ----
        float x0[CI], x1[CI];
#pragma unroll
        for (int i = 0; i < CI; ++i) {
            x0[i] = Ux[i * 256 + m0];
            x1[i] = Ux[i * 256 + m0 + 32];
        }
        __syncthreads();    // Ux reads done -> Up may overwrite
        // ---- stage P: px regs -> Up swizzled (proven R17 layout) ----
#pragma unroll
        for (int s = 0; s < 16; ++s) {
            const int id = t + 256 * s;
            const int r = id >> 4, ch = id & 15;
            bf16x4 bv;
#pragma unroll
            for (int j = 0; j < 4; ++j) bv[j] = (__bf16)px[s][j];
            *(bf16x4*)((char*)Up + r * 128
                       + ((((ch >> 1) ^ (r & 7)) << 4) | ((ch & 1) * 8))) = bv;
        }
        if (tt + 1 < NTILES) load_px(base0 + (tt + 1) * (NBLK * TILE_M));  // T14
        __syncthreads();
        // ---- B fragments (P^T) for rows m0, m0+32 ----
        bf16x8 bfA[4], bfB[4];
#pragma unroll
        for (int kq = 0; kq < 4; ++kq) {
            const int g = ((kq * 2 + hi) ^ (l31 & 7)) << 4;
            bfA[kq] = *(const bf16x8*)((const char*)Up + m0 * 128 + g);
            bfB[kq] = *(const bf16x8*)((const char*)Up + (m0 + 32) * 128 + g);
        }

        // ---- i-loop: full 32, A from LDS (broadcast across waves), 2-deep ----
        f32x2 oA[8] = {}, oB[8] = {};
        const char* abase = (const char*)Al + hi * 512 + l31 * 16;
        bf16x8 a0[4], a1[4];
        auto aload = [&](int i, bf16x8* buf) {
#pragma unroll
            for (int c = 0; c < 4; ++c)   // 4 x ds_read_b128, 1024B/wave-instr
                buf[c] = *(const bf16x8*)(abase + (size_t)i * 4096 + c * 1024);
        };
        const f32x2 zero2 = {0.0f, 0.0f};
        auto stepf = [&](const bf16x8* a, float xl, float xh) {
            f32x16 c0 = {}, c1 = {};
#pragma unroll
            for (int kq = 0; kq < 4; ++kq) {   // 2 independent MFMA chains
                c0 = __builtin_amdgcn_mfma_f32_32x32x16_bf16(a[kq], bfA[kq], c0, 0, 0, 0);
                c1 = __builtin_amdgcn_mfma_f32_32x32x16_bf16(a[kq], bfB[kq], c1, 0, 0, 0);
            }
            const f32x2 xl2 = {xl, xl}, xh2 = {xh, xh};
#pragma unroll
            for (int r = 0; r < 8; ++r) {      // VOP3P packed epilogue
                f32x2 p0 = {c0[2*r], c0[2*r + 1]};
                f32x2 p1 = {c1[2*r], c1[2*r + 1]};
                oA[r] += __builtin_elementwise_max(p0, zero2) * xl2;
                oB[r] += __builtin_elementwise_max(p1, zero2) * xh2;
            }
        };
        aload(0, a0);
        aload(1, a1);
#pragma unroll
        for (int ii = 0; ii < 16; ++ii) {      // static x-indices (rule #20)
            stepf(a0, x0[2*ii], x1[2*ii]);
            if (ii < 15) aload(2*ii + 2, a0);
            stepf(a1, x0[2*ii + 1], x1[2*ii + 1]);
            if (ii < 15) aload(2*ii + 3, a1);
        }

        // ---- direct stores (R17 pattern): full 128B lines per wave ----
        float* orow  = outg + (size_t)(tile0 + m0) * CO + 4 * hi;
        float* orow2 = orow + 32 * CO;
#pragma unroll
        for (int rq = 0; rq < 4; ++rq) {
            f32x4 vA, vB;
#pragma unroll
            for (int j = 0; j < 4; ++j) {
                vA[j] = oA[2*rq + (j >> 1)][j & 1];
                vB[j] = oB[2*rq + (j >> 1)][j & 1];
            }
            *(f32x4*)(orow  + 8 * rq) = vA;
            *(f32x4*)(orow2 + 8 * rq) = vB;
        }
    }
}

extern "C" void kernel_launch(void* const* d_in, const int* in_sizes, int n_in,
                              void* d_out, int out_size, void* d_ws, size_t ws_size,
                              hipStream_t stream)
{
    const float* X  = (const float*)d_in[0];
    const float* P  = (const float*)d_in[1];
    const float* Wk = (const float*)d_in[2];
    float* out = (float*)d_out;

    // opt-in to 160 KiB dynamic LDS (idempotent host-side attribute; no enqueue)
    hipFuncSetAttribute((const void*)cond_fused,
                        hipFuncAttributeMaxDynamicSharedMemorySize, LDS_BYTES);
    cond_fused<<<dim3(NBLK), dim3(WG_THREADS), LDS_BYTES, stream>>>(X, P, Wk, out);
}

// Round 22
// 36.215 us; speedup vs baseline: 3.2536x; 1.1353x over previous
//
#include <hip/hip_runtime.h>

#define CI 32
#define CO 32
#define PD 64
#define QDIM 1024
#define M_TOTAL (32*4096)
#define TILE_M 128                 // per WG: waves = (rg 0..1) x (ih 0..1)
#define NBLK (M_TOTAL/TILE_M)      // 1024 WGs
#define WG_THREADS 256
#define XLS 33                     // Xl[m][i]: 16-lane reads distinct banks + bcast
#define OLS 33                     // U.o[lane][r]: 2-way free

typedef float  f32x2  __attribute__((ext_vector_type(2)));
typedef float  f32x4  __attribute__((ext_vector_type(4)));
typedef __bf16 bf16x4 __attribute__((ext_vector_type(4)));
typedef __bf16 bf16x8 __attribute__((ext_vector_type(8)));

// ---- one-time: Wk -> wsG, 16x16x32 A-fragment-linear layout ----
// byte addr = i*4096 + qb*2048 + kh*1024 + g*256 + c*16  (g = lane>>4, c = lane&15)
// holding Wk[k = kh*32 + g*8 + j][q = i*32 + qb*16 + c] as bf16x8 over j.
__global__ __launch_bounds__(256)
void wk_pack16(const float* __restrict__ Wk, __bf16* __restrict__ wsG)
{
    __shared__ float tile[64][33];
    const int i  = blockIdx.x;          // 0..31
    const int q0 = i * 32;
    const int t  = threadIdx.x;
#pragma unroll
    for (int s = 0; s < 2; ++s) {
        const int idx = t + s * 256;
        const int k = idx >> 3, ch = idx & 7;
        f32x4 v = *(const f32x4*)(Wk + (size_t)k * QDIM + q0 + ch * 4);
        tile[k][ch*4+0] = v[0]; tile[k][ch*4+1] = v[1];
        tile[k][ch*4+2] = v[2]; tile[k][ch*4+3] = v[3];
    }
    __syncthreads();
    const int qq = t >> 3;              // 0..31
    const int g8 = t & 7;               // (kh,g)
    const int kh = g8 >> 2, g = g8 & 3;
    const int qb = qq >> 4, c = qq & 15;
    bf16x8 o;
#pragma unroll
    for (int j = 0; j < 8; ++j) o[j] = (__bf16)tile[kh*32 + g*8 + j][qq];
    *(bf16x8*)((char*)wsG + (size_t)i * 4096 + qb * 2048 + kh * 1024
               + g * 256 + c * 16) = o;
}

// R17 skeleton + 16x16x32 MFMA: 8 independent chains of depth 2 per step
// (vs 2 chains of depth 4 with 32x32x16). Targets the one untested in-loop
// dimension: MFMA dependent-issue latency exposure (loop time proven
// insensitive to A-source, occupancy, packing, decomposition — R20/R21).
// DO NOT: min-waves>=4 (R7/R16 spills), per-lane X global rows (R18),
// scalar Wk gathers in-loop (R6).
__global__ __launch_bounds__(WG_THREADS, 2)
void cond_dense_kernel(const float* __restrict__ Xg, const float* __restrict__ Pg,
                       const __bf16* __restrict__ wsG, float* __restrict__ outg)
{
    __shared__ union {
        __bf16 p[TILE_M * PD];       // 16384 B: P-tile (dead after bfr)
        float  o[2 * 64 * OLS];      // 16896 B: partial-sum exchange
    } U;
    __shared__ float Xl[TILE_M * XLS];   // 16896 B: X row-major [m][i]

    const int t   = threadIdx.x;
    const int l   = t & 63;
    const int w   = t >> 6;
    const int rg  = w & 1;          // row-group: rows rg*64 .. rg*64+63
    const int ih  = w >> 1;         // i-half: i in ih*16 .. ih*16+15
    const int c16 = l & 15;         // MFMA col (m mod 16)
    const int h4  = l >> 4;         // 0..3: k-octet / D-row group
    const int tile0 = blockIdx.x * TILE_M;
    const int mbase = rg * 64;

    // ---- stage: P[128][64] -> bf16 swizzled; X[128][32] -> Xl[m][i] ----
    {
        const float* Pb = Pg + (size_t)tile0 * PD;
#pragma unroll
        for (int s = 0; s < 8; ++s) {
            const int id = t + 256 * s;
            const int r = id >> 4, ch = id & 15;
            f32x4 v = *(const f32x4*)(Pb + (size_t)r * PD + ch * 4);
            bf16x4 bv;
#pragma unroll
            for (int j = 0; j < 4; ++j) bv[j] = (__bf16)v[j];
            char* dst = (char*)U.p + r * 128
                      + ((((ch >> 1) ^ (r & 7)) << 4) | ((ch & 1) * 8));
            *(bf16x4*)dst = bv;
        }
        const float* Xb = Xg + (size_t)tile0 * CI;
#pragma unroll
        for (int s = 0; s < 4; ++s) {
            const int id = t + 256 * s;
            const int r = id >> 3, ch = id & 7;
            f32x4 v = *(const f32x4*)(Xb + (size_t)r * CI + ch * 4);
#pragma unroll
            for (int j = 0; j < 4; ++j) Xl[r * XLS + ch * 4 + j] = v[j];
        }
    }
    __syncthreads();

    // ---- B fragments (P^T) for 4 m-quarters x 2 k-halves ----
    // B[k][m]: lane col m = mbase+mq*16+c16, k = kh*32 + h4*8 + j
    bf16x8 bfr[4][2];
#pragma unroll
    for (int mq = 0; mq < 4; ++mq) {
        const int row = mbase + mq * 16 + c16;
#pragma unroll
        for (int kh = 0; kh < 2; ++kh) {
            const int g = ((h4 + 4 * kh) ^ (row & 7)) << 4;
            bfr[mq][kh] = *(const bf16x8*)((const char*)U.p + row * 128 + g);
        }
    }

    // ---- i-loop over this wave's half: 16 steps, next-i prefetch ----
    f32x2 oacc[16] = {};   // [qb*8 + mq*2 + p]: 32 f32
    const char* abase = (const char*)wsG + (size_t)(ih * 16) * 4096
                      + h4 * 256 + c16 * 16;
    const float* xb = &Xl[(mbase + c16) * XLS + ih * 16];  // + mq*16*XLS

    bf16x8 aq[4], an[4];   // [qb*2+kh] current / next
    auto aload = [&](int il, bf16x8* buf) {
        const char* p = abase + (size_t)il * 4096;
        buf[0] = *(const bf16x8*)(p);           // qb0 kh0
        buf[1] = *(const bf16x8*)(p + 1024);    // qb0 kh1
        buf[2] = *(const bf16x8*)(p + 2048);    // qb1 kh0
        buf[3] = *(const bf16x8*)(p + 3072);    // qb1 kh1
    };
    const f32x2 zero2 = {0.0f, 0.0f};
    auto step = [&](const bf16x8* a, int il) {
        f32x2 x2[4];
#pragma unroll
        for (int mq = 0; mq < 4; ++mq) {
            const float x = xb[mq * 16 * XLS + il];
            x2[mq][0] = x; x2[mq][1] = x;
        }
#pragma unroll
        for (int qb = 0; qb < 2; ++qb) {
            f32x4 cc[4] = {};                    // 8 chains of depth 2 per i
#pragma unroll
            for (int mq = 0; mq < 4; ++mq) {
                cc[mq] = __builtin_amdgcn_mfma_f32_16x16x32_bf16(a[qb*2+0], bfr[mq][0], cc[mq], 0, 0, 0);
                cc[mq] = __builtin_amdgcn_mfma_f32_16x16x32_bf16(a[qb*2+1], bfr[mq][1], cc[mq], 0, 0, 0);
            }
#pragma unroll
            for (int mq = 0; mq < 4; ++mq) {
#pragma unroll
                for (int p = 0; p < 2; ++p) {
                    f32x2 pr = {cc[mq][2*p], cc[mq][2*p + 1]};
                    oacc[qb*8 + mq*2 + p] +=
                        __builtin_elementwise_max(pr, zero2) * x2[mq];
                }
            }
        }
    };

    aload(0, aq);
    aload(1, an);
#pragma unroll
    for (int ii = 0; ii < 8; ++ii) {
        step(aq, 2 * ii);
        if (ii < 7) aload(2 * ii + 2, aq);
        step(an, 2 * ii + 1);
        if (ii < 7) aload(2 * ii + 3, an);
    }

    // ---- combine partials: ih=1 publishes, ih=0 adds and stores ----
    __syncthreads();                   // bfr reads long done; U.p -> U.o
    const int ob = (rg * 64 + l) * OLS;
    if (ih == 1) {
#pragma unroll
        for (int r = 0; r < 16; ++r)
            *(f32x2*)&U.o[ob + 2*r] = oacc[r];
    }
    __syncthreads();
    if (ih == 0) {
#pragma unroll
        for (int r = 0; r < 16; ++r)
            oacc[r] += *(const f32x2*)&U.o[ob + 2*r];
        // direct stores: lane (h4,c16): row m = mbase+mq*16+c16, col qb*16+h4*4
#pragma unroll
        for (int qb = 0; qb < 2; ++qb) {
#pragma unroll
            for (int mq = 0; mq < 4; ++mq) {
                f32x4 v;
                v[0] = oacc[qb*8 + mq*2 + 0][0];
                v[1] = oacc[qb*8 + mq*2 + 0][1];
                v[2] = oacc[qb*8 + mq*2 + 1][0];
                v[3] = oacc[qb*8 + mq*2 + 1][1];
                float* orow = outg + (size_t)(tile0 + mbase + mq*16 + c16) * CO
                            + qb * 16 + h4 * 4;
                *(f32x4*)orow = v;
            }
        }
    }
}

extern "C" void kernel_launch(void* const* d_in, const int* in_sizes, int n_in,
                              void* d_out, int out_size, void* d_ws, size_t ws_size,
                              hipStream_t stream)
{
    const float* X  = (const float*)d_in[0];
    const float* P  = (const float*)d_in[1];
    const float* Wk = (const float*)d_in[2];
    float* out  = (float*)d_out;
    __bf16* wsG = (__bf16*)d_ws;   // 32*4096 B = 128 KB

    wk_pack16<<<dim3(CI), dim3(256), 0, stream>>>(Wk, wsG);
    cond_dense_kernel<<<dim3(NBLK), dim3(WG_THREADS), 0, stream>>>(X, P, wsG, out);
}